// Round 1
// baseline (240.987 us; speedup 1.0000x reference)
//
#include <hip/hip_runtime.h>

// YOLO head transform: p (8, 4*65, 128, 128) f32 -> out (8, 4*128*128, 65) f32.
// Per (b,a): 65 x 16384 -> 16384 x 65 transpose + cheap elementwise.
// Pure HBM-bound: 272.6 MB total -> ~43 us roofline at 6.3 TB/s.

namespace {
constexpr int kNA  = 4;
constexpr int kNC  = 60;
constexpr int kNCH = kNC + 5;     // 65 channels
constexpr int kNG  = 128;
constexpr int kTW  = 64;          // gx tile width (2 tiles per gy row)
constexpr int kThreads = 256;
constexpr int kRow = kNG * kNG;   // 16384 floats between channels in p
}

// One block = (b, a, gy, gx-half). LDS tile stored in EXACT output-linear
// order [s][c] (stride 65): store phase is a contiguous float4 copy
// (conflict-free b128 reads + perfectly coalesced dwordx4 stores).
// Load phase: float2 global loads along gx; LDS write lane-stride = 130
// floats == 2 (mod 32) -> 2-way bank aliasing only (free per m136).
__global__ __launch_bounds__(kThreads, 8)
void yolo_head_kernel(const float* __restrict__ p,
                      const float* __restrict__ anchors,
                      const int* __restrict__ img_dim,
                      float* __restrict__ out)
{
    __shared__ float tile[kTW * kNCH];   // 4160 floats = 16640 B

    const int blk  = blockIdx.x;
    const int half = blk & 1;
    const int gy   = (blk >> 1) & (kNG - 1);
    const int ba   = blk >> 8;           // blk / (2*kNG)
    const int a    = ba & (kNA - 1);
    const int b    = ba >> 2;
    const int gx0  = half * kTW;

    const float stride = (float)img_dim[0] / (float)kNG;   // 1024/128 = 8
    const float aw4 = 4.0f * anchors[2 * a];       // (2w)^2 * (anchor/stride) * stride
    const float ah4 = 4.0f * anchors[2 * a + 1];
    const float gyf = (float)gy;

    const int t = threadIdx.x;
    const float* __restrict__ pin =
        p + (((size_t)b * (kNA * kNCH) + (size_t)a * kNCH) * kNG + gy) * kNG + gx0;

    // ---- load + transform: 65 channels x 32 float2 = 2080 items ----
    for (int l = t; l < kNCH * (kTW / 2); l += kThreads) {
        const int c    = l >> 5;         // channel 0..64
        const int col2 = l & 31;
        const int s    = col2 * 2;       // gx within tile
        const float2 v = *reinterpret_cast<const float2*>(pin + (size_t)c * kRow + s);
        float r0 = v.x, r1 = v.y;
        if (c < 5) {
            const float s0 = 1.0f / (1.0f + expf(-v.x));
            const float s1 = 1.0f / (1.0f + expf(-v.y));
            if (c == 0) {
                r0 = (s0 + (float)(gx0 + s)) * stride;
                r1 = (s1 + (float)(gx0 + s + 1)) * stride;
            } else if (c == 1) {
                r0 = (s0 + gyf) * stride;
                r1 = (s1 + gyf) * stride;
            } else if (c == 2) {
                r0 = s0 * s0 * aw4;
                r1 = s1 * s1 * aw4;
            } else if (c == 3) {
                r0 = s0 * s0 * ah4;
                r1 = s1 * s1 * ah4;
            } else {                     // c == 4: objectness
                r0 = s0;
                r1 = s1;
            }
        }
        tile[s * kNCH + c]       = r0;
        tile[(s + 1) * kNCH + c] = r1;
    }

    __syncthreads();

    // ---- store: tile is output-linear -> contiguous 1040-float4 copy ----
    // chunk base = multiple of 64*65 floats -> 16B aligned.
    float4* __restrict__ op = reinterpret_cast<float4*>(
        out + (size_t)((((b * kNA + a) * kNG + gy) * kNG) + gx0) * kNCH);
    const float4* tp = reinterpret_cast<const float4*>(tile);
    for (int l = t; l < (kTW * kNCH) / 4; l += kThreads)
        op[l] = tp[l];
}

extern "C" void kernel_launch(void* const* d_in, const int* in_sizes, int n_in,
                              void* d_out, int out_size, void* d_ws, size_t ws_size,
                              hipStream_t stream)
{
    const float* p       = (const float*)d_in[0];
    const float* anchors = (const float*)d_in[1];
    const int*   img_dim = (const int*)d_in[2];
    float* out = (float*)d_out;

    const int bs = in_sizes[0] / (kNA * kNCH * kNG * kNG);   // 8
    const int nblocks = bs * kNA * kNG * 2;                  // 8192
    yolo_head_kernel<<<nblocks, kThreads, 0, stream>>>(p, anchors, img_dim, out);
}

// Round 2
// 237.162 us; speedup vs baseline: 1.0161x; 1.0161x over previous
//
#include <hip/hip_runtime.h>

// YOLO head transform: p (8, 4*65, 128, 128) f32 -> out (8, 4*128*128, 65) f32.
// Per (b,a): 65 x 16384 -> 16384 x 65 transpose + cheap elementwise (5 of 65
// channels get sigmoid/box math). Pure HBM-bound: ~273 MB total.
//
// R1 lesson: VGPR_Count=12 => compiler serialized loads (1 in flight/wave,
// 2.47 TB/s). This version batches 5 float4 loads/thread into named regs
// (one clause, ~5 KB in flight per wave) before any dependent use.

namespace {
constexpr int kNA  = 4;
constexpr int kNC  = 60;
constexpr int kNCH = kNC + 5;          // 65 channels
constexpr int kNG  = 128;
constexpr int kThreads = 512;          // 8 waves
constexpr int kRow  = kNG * kNG;       // 16384 floats between channels in p
constexpr int kItems = kNCH * (kNG / 4);           // 2080 float4 items/block
constexpr int kIter  = (kItems + kThreads - 1) / kThreads;  // 5 (last predicated)
}

// One block = (b, a, gy) full 128-wide row. LDS tile in EXACT output-linear
// order [s][c] (stride 65): store phase is a contiguous float4 copy
// (sequential b128 reads, conflict-free; perfectly coalesced dwordx4 stores).
// Load phase: float4 along gx; LDS write lane-stride = 260 floats == 4
// (mod 32) -> 4-way bank conflict (1.58x on a tiny fraction of cycles, ok).
__global__ __launch_bounds__(kThreads, 8)
void yolo_head_kernel(const float* __restrict__ p,
                      const float* __restrict__ anchors,
                      const int* __restrict__ img_dim,
                      float* __restrict__ out)
{
    __shared__ float tile[kNG * kNCH];   // 8320 floats = 33.3 KB

    const int blk = blockIdx.x;
    const int gy  = blk & (kNG - 1);
    const int ba  = blk >> 7;
    const int a   = ba & (kNA - 1);
    const int b   = ba >> 2;

    const float stride = (float)img_dim[0] / (float)kNG;   // 1024/128 = 8
    const float aw4 = 4.0f * anchors[2 * a];     // (2w)^2*(anchor/stride)*stride
    const float ah4 = 4.0f * anchors[2 * a + 1];
    const float gyf = (float)gy;

    const int t = threadIdx.x;
    const float* __restrict__ pin =
        p + (((size_t)b * (kNA * kNCH) + (size_t)a * kNCH) * kNG + gy) * kNG;

    // ---- phase 1a: issue ALL loads as one clause (5 float4 in flight) ----
    float4 v[kIter];
    #pragma unroll
    for (int i = 0; i < kIter; ++i) {
        const int l = t + i * kThreads;
        if (l < kItems)
            v[i] = *reinterpret_cast<const float4*>(
                pin + (size_t)(l >> 5) * kRow + (size_t)(l & 31) * 4);
    }

    // ---- phase 1b: transform + transpose into LDS ----
    #pragma unroll
    for (int i = 0; i < kIter; ++i) {
        const int l = t + i * kThreads;
        if (l >= kItems) continue;
        const int c = l >> 5;            // channel 0..64
        const int s = (l & 31) * 4;      // gx within row
        float r[4] = {v[i].x, v[i].y, v[i].z, v[i].w};
        if (c < 5) {
            #pragma unroll
            for (int j = 0; j < 4; ++j) {
                const float sg = 1.0f / (1.0f + expf(-r[j]));
                if (c == 0)      r[j] = (sg + (float)(s + j)) * stride;
                else if (c == 1) r[j] = (sg + gyf) * stride;
                else if (c == 2) r[j] = sg * sg * aw4;
                else if (c == 3) r[j] = sg * sg * ah4;
                else             r[j] = sg;            // objectness sigmoid
            }
        }
        #pragma unroll
        for (int j = 0; j < 4; ++j)
            tile[(s + j) * kNCH + c] = r[j];
    }

    __syncthreads();

    // ---- phase 2: tile is output-linear -> contiguous float4 copy ----
    // block output base = gy*128*65 floats = 33280 B -> 16B aligned.
    float4* __restrict__ op = reinterpret_cast<float4*>(
        out + (size_t)(((b * kNA + a) * kNG + gy) * kNG) * kNCH);
    const float4* tp = reinterpret_cast<const float4*>(tile);
    #pragma unroll
    for (int i = 0; i < kIter; ++i) {
        const int l = t + i * kThreads;
        if (l < kItems) op[l] = tp[l];
    }
}

extern "C" void kernel_launch(void* const* d_in, const int* in_sizes, int n_in,
                              void* d_out, int out_size, void* d_ws, size_t ws_size,
                              hipStream_t stream)
{
    const float* p       = (const float*)d_in[0];
    const float* anchors = (const float*)d_in[1];
    const int*   img_dim = (const int*)d_in[2];
    float* out = (float*)d_out;

    const int bs = in_sizes[0] / (kNA * kNCH * kNG * kNG);   // 8
    const int nblocks = bs * kNA * kNG;                      // 4096
    yolo_head_kernel<<<nblocks, kThreads, 0, stream>>>(p, anchors, img_dim, out);
}

// Round 3
// 236.780 us; speedup vs baseline: 1.0178x; 1.0016x over previous
//
#include <hip/hip_runtime.h>

// YOLO head transform: p (8, 4*65, 128, 128) f32 -> out (8, 4*128*128, 65) f32.
// Per (b,a): 65 x 16384 -> 16384 x 65 transpose + cheap elementwise (5 of 65
// channels get sigmoid/box math). HBM-bound: ~273 MB total -> ~43 us floor.
//
// R1: VGPR_Count=12, loads serialized -> 2.5 TB/s, 83 us.
// R2: 5-deep clause BUT __launch_bounds__(512,8) capped VGPRs at 64 ->
//     compiler sank loads back next to uses; no improvement (~79 us).
// R3 (this): 256 threads, __launch_bounds__(256,4) -> 128-VGPR budget;
//     9-deep float4 clause per thread (~9 KB in flight per wave, 16 waves/CU).
//     Address stride between clause loads is a constant 512 KB.

namespace {
constexpr int kNA  = 4;
constexpr int kNC  = 60;
constexpr int kNCH = kNC + 5;          // 65 channels
constexpr int kNG  = 128;
constexpr int kThreads = 256;          // 4 waves
constexpr int kRow  = kNG * kNG;       // 16384 floats between channels in p
constexpr int kItems = kNCH * (kNG / 4);   // 2080 float4 items per block
constexpr int kIter  = 9;                  // 8 full + 1 tail (threads 0..31)
}

// One block = (b, a, gy) full 128-wide row. LDS tile in EXACT output-linear
// order [s][c] (stride 65): store phase is a contiguous float4 copy
// (sequential b128 reads, conflict-free; perfectly coalesced dwordx4 stores).
// Item l: c = l>>5 (channel), col = l&31, s = 4*col (gx). For l = t + 256*i:
// c = (t>>5) + 8*i, col = t&31  ->  per-i global address step = 8*kRow floats.
__global__ __launch_bounds__(kThreads, 4)
void yolo_head_kernel(const float* __restrict__ p,
                      const float* __restrict__ anchors,
                      const int* __restrict__ img_dim,
                      float* __restrict__ out)
{
    __shared__ float tile[kNG * kNCH];   // 8320 floats = 33.3 KB

    const int blk = blockIdx.x;
    const int gy  = blk & (kNG - 1);
    const int ba  = blk >> 7;
    const int a   = ba & (kNA - 1);
    const int b   = ba >> 2;

    const float stride = (float)img_dim[0] / (float)kNG;   // 1024/128 = 8
    const float aw4 = 4.0f * anchors[2 * a];     // (2w)^2*(anchor/stride)*stride
    const float ah4 = 4.0f * anchors[2 * a + 1];
    const float gyf = (float)gy;

    const int t   = threadIdx.x;
    const int c0  = t >> 5;              // channel of iter 0
    const int col = t & 31;              // float4 column within row (constant)
    const float* __restrict__ pin =
        p + (((size_t)b * (kNA * kNCH) + (size_t)a * kNCH) * kNG + gy) * kNG;

    // ---- phase 1a: one clause of 9 float4 loads (last predicated t<32) ----
    const float* __restrict__ src = pin + (size_t)c0 * kRow + (size_t)col * 4;
    float4 v[kIter];
    #pragma unroll
    for (int i = 0; i < kIter; ++i) {
        if (i < kIter - 1 || t < (kItems - (kIter - 1) * kThreads))
            v[i] = *reinterpret_cast<const float4*>(src + (size_t)i * 8 * kRow);
    }

    // ---- phase 1b: transform + transpose into LDS ----
    const int s = col * 4;
    #pragma unroll
    for (int i = 0; i < kIter; ++i) {
        if (i == kIter - 1 && t >= (kItems - (kIter - 1) * kThreads)) continue;
        const int c = c0 + 8 * i;
        float r[4] = {v[i].x, v[i].y, v[i].z, v[i].w};
        if (c < 5) {
            #pragma unroll
            for (int j = 0; j < 4; ++j) {
                const float sg = 1.0f / (1.0f + expf(-r[j]));
                if (c == 0)      r[j] = (sg + (float)(s + j)) * stride;
                else if (c == 1) r[j] = (sg + gyf) * stride;
                else if (c == 2) r[j] = sg * sg * aw4;
                else if (c == 3) r[j] = sg * sg * ah4;
                else             r[j] = sg;            // objectness sigmoid
            }
        }
        #pragma unroll
        for (int j = 0; j < 4; ++j)
            tile[(s + j) * kNCH + c] = r[j];
    }

    __syncthreads();

    // ---- phase 2: tile is output-linear -> contiguous float4 copy ----
    // block output base = 128*65 floats = 33280 B -> 16B aligned.
    float4* __restrict__ op = reinterpret_cast<float4*>(
        out + (size_t)(((b * kNA + a) * kNG + gy) * kNG) * kNCH);
    const float4* tp = reinterpret_cast<const float4*>(tile);
    #pragma unroll
    for (int i = 0; i < kIter; ++i) {
        const int l = t + i * kThreads;
        if (l < kItems) op[l] = tp[l];
    }
}

extern "C" void kernel_launch(void* const* d_in, const int* in_sizes, int n_in,
                              void* d_out, int out_size, void* d_ws, size_t ws_size,
                              hipStream_t stream)
{
    const float* p       = (const float*)d_in[0];
    const float* anchors = (const float*)d_in[1];
    const int*   img_dim = (const int*)d_in[2];
    float* out = (float*)d_out;

    const int bs = in_sizes[0] / (kNA * kNCH * kNG * kNG);   // 8
    const int nblocks = bs * kNA * kNG;                      // 4096
    yolo_head_kernel<<<nblocks, kThreads, 0, stream>>>(p, anchors, img_dim, out);
}

// Round 4
// 236.460 us; speedup vs baseline: 1.0191x; 1.0014x over previous
//
#include <hip/hip_runtime.h>
#include <cstdint>

// YOLO head: p (8, 4*65, 128, 128) f32 -> out (8, 4*128*128, 65) f32.
// Transpose + cheap elementwise; HBM-bound (~273 MB logical, ~205 MB HBM-visible).
//
// R1: sync float2 loads, VGPR=12 -> 83 us (2.5 TB/s).
// R2/R3: register load clauses (5-deep, 9-deep) -> ~79 us. NULL x2: clause depth
//        was never the lever; the sync read->use round-trip is.
// R4 (this): async global->LDS staging. Block = (b,a,gy-pair); 65 channels x
//        1 KB contiguous each via global_load_lds width=16 (65 loads ~66 KB
//        queued per block, single vmcnt drain at __syncthreads). LDS transpose
//        (2-way-free banks both sides), then dense float4 store phase.

namespace {
constexpr int kNA      = 4;
constexpr int kNCH     = 65;
constexpr int kNG      = 128;
constexpr int kThreads = 512;                 // 8 waves
constexpr int kPix     = 256;                 // 2 gy rows x 128 gx per tile
constexpr int kTileF   = kNCH * kPix;         // 16640 floats
constexpr int kLdsBytes= 2 * kTileF * 4;      // 133120 B dynamic LDS
}

#define AS1 __attribute__((address_space(1)))
#define AS3 __attribute__((address_space(3)))

__device__ __forceinline__ float sigm(float v) { return 1.0f / (1.0f + expf(-v)); }

__global__ __launch_bounds__(kThreads, 1)
void yolo_head_kernel(const float* __restrict__ p,
                      const float* __restrict__ anchors,
                      const int* __restrict__ img_dim,
                      float* __restrict__ out)
{
    extern __shared__ float lds[];
    float* in_t  = lds;             // [65][256] raw, channel-major (gload_lds linear)
    float* out_t = lds + kTileF;    // [256][65] output-linear

    const int bid = blockIdx.x;
    const int gyp = bid & 63;                 // gy pair index
    const int ba  = bid >> 6;
    const int a   = ba & (kNA - 1);
    const int b   = ba >> 2;
    const int gy0 = gyp * 2;

    const int t    = threadIdx.x;
    const int wv   = t >> 6;                  // wave id 0..7
    const int lane = t & 63;

    // ---- phase 1: async global->LDS, 65 channels x 1 KB contiguous ----
    // wave-uniform LDS dest (in_t + c*256), per-lane global src (+lane*16B).
    const float* base = p + ((size_t)(b * (kNA*kNCH) + a * kNCH) * kNG + gy0) * kNG;
    #pragma unroll
    for (int i = 0; i < 9; ++i) {
        const int c = wv + i * 8;             // wave-uniform
        if (c < kNCH) {
            const float* src = base + (size_t)c * (kNG * kNG) + lane * 4;
            __builtin_amdgcn_global_load_lds((const AS1 uint32_t*)src,
                                             (AS3 uint32_t*)(in_t + c * kPix),
                                             16, 0, 0);
        }
    }

    const float stride = (float)img_dim[0] / (float)kNG;   // 8.0
    const float aw4 = 4.0f * anchors[2 * a];   // (2w)^2*(anchor/stride)*stride
    const float ah4 = 4.0f * anchors[2 * a + 1];

    __syncthreads();   // compiler emits s_waitcnt vmcnt(0) here: tile resident

    // ---- phase 2: LDS transpose + transform ----
    // item l = (s in [0,256), q in [0,17)); wave lanes span consecutive s ->
    // reads lane-stride 4 B (free), writes lane-stride 260 B == 1 bank (free).
    #pragma unroll
    for (int i = 0; i < 9; ++i) {
        const int l = t + i * kThreads;
        if (l < kPix * 17) {
            const int s = l & (kPix - 1);     // pixel within tile
            const int q = l >> 8;             // channel quad 0..16
            if (q < 16) {
                const int c0 = 4 * q;
                float r0 = in_t[(c0 + 0) * kPix + s];
                float r1 = in_t[(c0 + 1) * kPix + s];
                float r2 = in_t[(c0 + 2) * kPix + s];
                float r3 = in_t[(c0 + 3) * kPix + s];
                if (q == 0) {                 // c = 0..3: x,y,w,h
                    const float gx  = (float)(s & (kNG - 1));
                    const float gyf = (float)(gy0 + (s >> 7));
                    r0 = (sigm(r0) + gx) * stride;
                    r1 = (sigm(r1) + gyf) * stride;
                    float sg = sigm(r2); r2 = sg * sg * aw4;
                    sg = sigm(r3);       r3 = sg * sg * ah4;
                } else if (q == 1) {          // c = 4: objectness
                    r0 = sigm(r0);
                }
                float* o = out_t + s * kNCH + c0;
                o[0] = r0; o[1] = r1; o[2] = r2; o[3] = r3;
            } else {                          // c = 64 tail channel
                out_t[s * kNCH + 64] = in_t[64 * kPix + s];
            }
        }
    }

    __syncthreads();

    // ---- phase 3: dense coalesced store (out_t is output-linear) ----
    // block base = (ba*16384 + gy0*128)*65 floats; gy0 even -> 16B aligned.
    float4* __restrict__ op = reinterpret_cast<float4*>(
        out + (size_t)(ba * (kNG * kNG) + gy0 * kNG) * kNCH);
    const float4* tp = reinterpret_cast<const float4*>(out_t);
    #pragma unroll
    for (int i = 0; i < 9; ++i) {
        const int f = t + i * kThreads;
        if (f < kTileF / 4) op[f] = tp[f];
    }
}

extern "C" void kernel_launch(void* const* d_in, const int* in_sizes, int n_in,
                              void* d_out, int out_size, void* d_ws, size_t ws_size,
                              hipStream_t stream)
{
    const float* p       = (const float*)d_in[0];
    const float* anchors = (const float*)d_in[1];
    const int*   img_dim = (const int*)d_in[2];
    float* out = (float*)d_out;

    // >64 KB dynamic LDS opt-in; host-side, idempotent, graph-capture safe.
    (void)hipFuncSetAttribute((const void*)yolo_head_kernel,
                              hipFuncAttributeMaxDynamicSharedMemorySize, kLdsBytes);

    const int bs = in_sizes[0] / (kNA * kNCH * kNG * kNG);   // 8
    const int nblocks = bs * kNA * (kNG / 2);                // 2048
    yolo_head_kernel<<<nblocks, kThreads, kLdsBytes, stream>>>(p, anchors, img_dim, out);
}

// Round 9
// 236.137 us; speedup vs baseline: 1.0205x; 1.0014x over previous
//
#include <hip/hip_runtime.h>
#include <cstdint>

// YOLO head: p (8, 4*65, 128, 128) f32 -> out (8, 4*128*128, 65) f32.
// Transpose + cheap elementwise; HBM-bound (~273 MB logical).
//
// R1: sync float2 loads, 72% occ            -> 82.6 us, 2.47 TB/s
// R2/R3: 5/9-deep register load clauses     -> ~79 us (null x2)
// R4: async global_load_lds, 17% occ        -> 83.6 us, 2.45 TB/s (null)
//   Four different CU-side structures, identical BW => limiter is the memory
//   system serving this mix, not the CU side. FETCH == exactly half the input
//   every round: L3 holds half the input at kernel start, and our output
//   write-allocates evict input ahead of the read front.
// R5-R7: acquisition timeouts. R8: __builtin_nontemporal_store rejects HIP's
//   float4 (class type) -> compile fail. This round: identical probe with a
//   native ext_vector_type(4) float for the nt stores. Single-variable A/B
//   vs R4: nt (no-allocate) output stores stop evicting resident input.

namespace {
constexpr int kNA      = 4;
constexpr int kNCH     = 65;
constexpr int kNG      = 128;
constexpr int kThreads = 512;                 // 8 waves
constexpr int kPix     = 256;                 // 2 gy rows x 128 gx per tile
constexpr int kTileF   = kNCH * kPix;         // 16640 floats
constexpr int kLdsBytes= 2 * kTileF * 4;      // 133120 B dynamic LDS
}

typedef float f32x4 __attribute__((ext_vector_type(4)));   // nt-builtin-compatible

#define AS1 __attribute__((address_space(1)))
#define AS3 __attribute__((address_space(3)))

__device__ __forceinline__ float sigm(float v) { return 1.0f / (1.0f + expf(-v)); }

__global__ __launch_bounds__(kThreads, 1)
void yolo_head_kernel(const float* __restrict__ p,
                      const float* __restrict__ anchors,
                      const int* __restrict__ img_dim,
                      float* __restrict__ out)
{
    extern __shared__ float lds[];
    float* in_t  = lds;             // [65][256] raw, channel-major (gload_lds linear)
    float* out_t = lds + kTileF;    // [256][65] output-linear

    const int bid = blockIdx.x;
    const int gyp = bid & 63;                 // gy pair index
    const int ba  = bid >> 6;
    const int a   = ba & (kNA - 1);
    const int b   = ba >> 2;
    const int gy0 = gyp * 2;

    const int t    = threadIdx.x;
    const int wv   = t >> 6;                  // wave id 0..7
    const int lane = t & 63;

    // ---- phase 1: async global->LDS, 65 channels x 1 KB contiguous ----
    const float* base = p + ((size_t)(b * (kNA*kNCH) + a * kNCH) * kNG + gy0) * kNG;
    #pragma unroll
    for (int i = 0; i < 9; ++i) {
        const int c = wv + i * 8;             // wave-uniform
        if (c < kNCH) {
            const float* src = base + (size_t)c * (kNG * kNG) + lane * 4;
            __builtin_amdgcn_global_load_lds((const AS1 uint32_t*)src,
                                             (AS3 uint32_t*)(in_t + c * kPix),
                                             16, 0, 0);
        }
    }

    const float stride = (float)img_dim[0] / (float)kNG;   // 8.0
    const float aw4 = 4.0f * anchors[2 * a];   // (2w)^2*(anchor/stride)*stride
    const float ah4 = 4.0f * anchors[2 * a + 1];

    __syncthreads();   // vmcnt(0) drain: tile resident

    // ---- phase 2: LDS transpose + transform ----
    #pragma unroll
    for (int i = 0; i < 9; ++i) {
        const int l = t + i * kThreads;
        if (l < kPix * 17) {
            const int s = l & (kPix - 1);     // pixel within tile
            const int q = l >> 8;             // channel quad 0..16
            if (q < 16) {
                const int c0 = 4 * q;
                float r0 = in_t[(c0 + 0) * kPix + s];
                float r1 = in_t[(c0 + 1) * kPix + s];
                float r2 = in_t[(c0 + 2) * kPix + s];
                float r3 = in_t[(c0 + 3) * kPix + s];
                if (q == 0) {                 // c = 0..3: x,y,w,h
                    const float gx  = (float)(s & (kNG - 1));
                    const float gyf = (float)(gy0 + (s >> 7));
                    r0 = (sigm(r0) + gx) * stride;
                    r1 = (sigm(r1) + gyf) * stride;
                    float sg = sigm(r2); r2 = sg * sg * aw4;
                    sg = sigm(r3);       r3 = sg * sg * ah4;
                } else if (q == 1) {          // c = 4: objectness
                    r0 = sigm(r0);
                }
                float* o = out_t + s * kNCH + c0;
                o[0] = r0; o[1] = r1; o[2] = r2; o[3] = r3;
            } else {                          // c = 64 tail channel
                out_t[s * kNCH + 64] = in_t[64 * kPix + s];
            }
        }
    }

    __syncthreads();

    // ---- phase 3: dense coalesced NON-TEMPORAL store (write-once data) ----
    // Only change vs R4: nt stores (no-allocate) so output doesn't evict the
    // L3-resident input during the kernel.
    f32x4* __restrict__ op = reinterpret_cast<f32x4*>(
        out + (size_t)(ba * (kNG * kNG) + gy0 * kNG) * kNCH);
    const f32x4* tp = reinterpret_cast<const f32x4*>(out_t);
    #pragma unroll
    for (int i = 0; i < 9; ++i) {
        const int f = t + i * kThreads;
        if (f < kTileF / 4)
            __builtin_nontemporal_store(tp[f], op + f);
    }
}

extern "C" void kernel_launch(void* const* d_in, const int* in_sizes, int n_in,
                              void* d_out, int out_size, void* d_ws, size_t ws_size,
                              hipStream_t stream)
{
    const float* p       = (const float*)d_in[0];
    const float* anchors = (const float*)d_in[1];
    const int*   img_dim = (const int*)d_in[2];
    float* out = (float*)d_out;

    // >64 KB dynamic LDS opt-in; host-side, idempotent, graph-capture safe.
    (void)hipFuncSetAttribute((const void*)yolo_head_kernel,
                              hipFuncAttributeMaxDynamicSharedMemorySize, kLdsBytes);

    const int bs = in_sizes[0] / (kNA * kNCH * kNG * kNG);   // 8
    const int nblocks = bs * kNA * (kNG / 2);                // 2048
    yolo_head_kernel<<<nblocks, kThreads, kLdsBytes, stream>>>(p, anchors, img_dim, out);
}